// Round 3
// baseline (371.275 us; speedup 1.0000x reference)
//
#include <hip/hip_runtime.h>

// Conv4d: x(2,8,16,40,40,40) f32 * w(3,32,8,3,3,3) + bias(3,32) -> out(2,32,16,40,40,40) f32
// Round 4b: 2-phase software pipeline (double-buffered halo, deferred vmcnt drain),
//           flattened 3-stage sequence (no runtime loop / lambdas).
//   prep_xw: fused x-transpose (blocks <9261) + weight-fragment prep (blocks >=9261).
//   main:    block=(b,o,d,h-tile8), 256 thr (4 waves); wave = 32co x 80n via mfma_f32_16x16x32_bf16.
//           Halo double-buffered in LDS (2 x 20160B): stage(kt+1) issued BEFORE compute(kt);
//           the vmcnt(0) drain at the trailing __syncthreads overlaps the MFMA K-loop.
//           A-frags read per-s directly from wf (L1/L2-hot, coalesced 1024B/wave) -- no LDS.

typedef unsigned int u32;
typedef unsigned short u16;
typedef __attribute__((ext_vector_type(8))) short short8;
typedef __attribute__((ext_vector_type(4))) float f32x4;

#define XT_OFF_BYTES 65536
// x_t strides in elements (bf16): ci 1, wp 8, hp 336, dp 14112, t 592704, b 9483264

__device__ __forceinline__ u32 bf16r(float f) {
    u32 u = __float_as_uint(f);
    return (u + 0x7FFFu + ((u >> 16) & 1u)) >> 16;
}

__device__ __forceinline__ void glds16(const void* g, void* l) {
    __builtin_amdgcn_global_load_lds((const __attribute__((address_space(1))) u32*)g,
                                     (__attribute__((address_space(3))) u32*)l, 16, 0, 0);
}

// ---------- fused pre-kernel: x transpose/pad/convert + weight A-fragment prep ----------
__global__ __launch_bounds__(256) void prep_xw(const float* __restrict__ x,
                                               const float* __restrict__ wgt,
                                               u16* __restrict__ xtp,
                                               u16* __restrict__ wf) {
    if (blockIdx.x >= 9261) {
        // ---- weights -> A-fragment order: Wf[kt][s 7][mt 2][lane 64][j 8], K=216 pad 224 ----
        const int idx = (blockIdx.x - 9261) * 256 + threadIdx.x;   // 21504 total = 3*14*512
        const int kt = idx / 7168;
        const int r  = idx - kt * 7168;
        const int s2 = r >> 9;              // s*2 + mt
        const int l  = (r >> 3) & 63;
        const int j  = r & 7;
        const int co = (s2 & 1) * 16 + (l & 15);
        const int k  = (s2 >> 1) * 32 + (l >> 4) * 8 + j;
        u32 v = 0;
        if (k < 216) {
            const int ci = k & 7;
            const int combo = k >> 3;                         // (kd,kh,kw)
            const int kd = combo / 9;
            const int r9 = combo - kd * 9;
            const int kh = r9 / 3;
            const int kw = r9 - kh * 3;
            v = bf16r(wgt[((kt * 32 + co) * 8 + ci) * 27 + kd * 9 + kh * 3 + kw]);
        }
        wf[idx] = (u16)v;
        return;
    }
    // ---- x -> x_t[b][t][dp 42][hp 42][wp 42][ci 8] bf16, zero-padded halo ----
    const int c = blockIdx.x * 256 + threadIdx.x;        // cell over [b][t][dp][hp][wp], 2370816 total
    int wp = c % 42;
    int tmp = c / 42;
    const int hp = tmp % 42; tmp /= 42;
    const int dp = tmp % 42; tmp /= 42;
    const int t  = tmp % 16;
    const int b  = tmp / 16;
    const int wa = wp - 1, ha = hp - 1, da = dp - 1;
    u32 q0 = 0, q1 = 0, q2 = 0, q3 = 0;
    if ((unsigned)wa < 40u && (unsigned)ha < 40u && (unsigned)da < 40u) {
        const float* xp = x + ((b * 8) * 16 + t) * 64000 + da * 1600 + ha * 40 + wa;
        float v0 = xp[0];
        float v1 = xp[1024000];
        float v2 = xp[2048000];
        float v3 = xp[3072000];
        float v4 = xp[4096000];
        float v5 = xp[5120000];
        float v6 = xp[6144000];
        float v7 = xp[7168000];
        q0 = bf16r(v0) | (bf16r(v1) << 16);
        q1 = bf16r(v2) | (bf16r(v3) << 16);
        q2 = bf16r(v4) | (bf16r(v5) << 16);
        q3 = bf16r(v6) | (bf16r(v7) << 16);
    }
    uint4 q; q.x = q0; q.y = q1; q.z = q2; q.w = q3;
    *(uint4*)(xtp + (size_t)c * 8) = q;
}

// ---------- main kernel ----------
__global__ __launch_bounds__(256, 3) void conv4d_mfma(
    const u16* __restrict__ xtp, const u16* __restrict__ wf,
    const float* __restrict__ bias, float* __restrict__ out)
{
    __shared__ __align__(16) u16 sHalo[2][10080];  // 2 x 20160 B: [d'3][h'10][w'42][ci8]
    __shared__ float sBsum[32];

    const int tid  = threadIdx.x;
    const int lane = tid & 63;
    const int wid  = tid >> 6;          // 0..3
    const int bi   = blockIdx.x;
    const int h0   = (bi % 5) * 8;
    const int d    = (bi / 5) % 40;
    const int o    = (bi / 200) % 16;
    const int b    = bi / 3200;

    if (tid < 32) {
        float s = 0.f;
        for (int kt = 0; kt < 3; ++kt) {
            int t = o + kt - 1;
            if ((unsigned)t < 16u) s += bias[kt * 32 + tid];
        }
        sBsum[tid] = s;
    }

    const int quad = lane >> 4;
    const int nl   = lane & 15;

    // per-lane n positions (5 n-tiles of 16, 80 n per wave)
    int lb[5];
#pragma unroll
    for (int tl = 0; tl < 5; ++tl) {
        int n = wid * 80 + tl * 16 + nl;   // 0..319
        int hh = n / 40;
        int ww = n - hh * 40;
        lb[tl] = (hh * 42 + ww) * 16;      // byte offset of cell (h'=hh, w'=ww) at d'=0
    }

    // per-lane combo offset per K-step (combo = 4s + quad), bytes
    int offs7[7];
#pragma unroll
    for (int s = 0; s < 7; ++s) {
        const int c0 = 4 * s;
        int O0 = (c0+0 < 27) ? (((c0+0)/9)*420 + (((c0+0)%9)/3)*42 + ((c0+0)%3)) * 16 : 0;
        int O1 = (c0+1 < 27) ? (((c0+1)/9)*420 + (((c0+1)%9)/3)*42 + ((c0+1)%3)) * 16 : 0;
        int O2 = (c0+2 < 27) ? (((c0+2)/9)*420 + (((c0+2)%9)/3)*42 + ((c0+2)%3)) * 16 : 0;
        int O3 = (c0+3 < 27) ? (((c0+3)/9)*420 + (((c0+3)%9)/3)*42 + ((c0+3)%3)) * 16 : 0;
        offs7[s] = (quad & 2) ? ((quad & 1) ? O3 : O2) : ((quad & 1) ? O1 : O0);
    }

    const f32x4 zero = {0.f, 0.f, 0.f, 0.f};
    f32x4 acc[2][5];
#pragma unroll
    for (int mt = 0; mt < 2; ++mt)
#pragma unroll
        for (int tl = 0; tl < 5; ++tl) acc[mt][tl] = zero;

    // valid kt range: t = o + kt - 1 in [0,16)
    const int kt_lo = (o == 0)  ? 1 : 0;
    const int kt_hi = (o == 15) ? 1 : 2;
    const int nkt   = kt_hi - kt_lo + 1;     // 2 or 3

// stage halo for time-plane (o+kt-1) into DST: 1260 x 16B chunks
#define STAGE(KT, DST)                                                                   \
    {                                                                                    \
        const int t_ = o + (KT) - 1;                                                     \
        const u16* gbase_ = xtp + (size_t)(b * 16 + t_) * 592704 + h0 * 336;             \
        const int jw_ = wid * 315;                                                       \
        _Pragma("unroll")                                                                \
        for (int i_ = 0; i_ < 5; ++i_) {                                                 \
            const int j_ = jw_ + i_ * 64 + lane;                                         \
            if (i_ < 4 || lane < 59) {                                                   \
                const int dpp_ = j_ / 420;                                               \
                const int r_ = j_ - dpp_ * 420;                                          \
                glds16(gbase_ + (d + dpp_) * 14112 + r_ * 8,                             \
                       (char*)(DST) + (jw_ + i_ * 64) * 16);                             \
            }                                                                            \
        }                                                                                \
    }

// K-loop body: 7 steps of K=32 (4 combos/step); A-frags direct from global (L1/L2-hot)
#define COMPUTE(KT, BUF)                                                                 \
    {                                                                                    \
        const u16* wfk_ = wf + (KT) * 7168;                                              \
        _Pragma("unroll")                                                                \
        for (int s_ = 0; s_ < 7; ++s_) {                                                 \
            const short8 a0_ = *(const short8*)(wfk_ + s_ * 1024 + lane * 8);            \
            const short8 a1_ = *(const short8*)(wfk_ + s_ * 1024 + 512 + lane * 8);      \
            const int off_ = offs7[s_];                                                  \
            _Pragma("unroll")                                                            \
            for (int tl_ = 0; tl_ < 5; ++tl_) {                                          \
                const short8 bf_ = *(const short8*)((const char*)(BUF) + lb[tl_] + off_);\
                acc[0][tl_] = __builtin_amdgcn_mfma_f32_16x16x32_bf16(a0_, bf_, acc[0][tl_], 0, 0, 0); \
                acc[1][tl_] = __builtin_amdgcn_mfma_f32_16x16x32_bf16(a1_, bf_, acc[1][tl_], 0, 0, 0); \
            }                                                                            \
        }                                                                                \
    }

    // flattened 2-deep pipeline over 2 or 3 valid kt (all branches block-uniform)
    STAGE(kt_lo, sHalo[0]);
    __syncthreads();                           // drain prologue stage (also covers sBsum)

    STAGE(kt_lo + 1, sHalo[1]);                // issue next-tile loads, no wait
    COMPUTE(kt_lo, sHalo[0]);
    __syncthreads();                           // vmcnt(0) drain lands AFTER the MFMA K-loop

    if (nkt == 3) {
        STAGE(kt_lo + 2, sHalo[0]);
        COMPUTE(kt_lo + 1, sHalo[1]);
        __syncthreads();
        COMPUTE(kt_lo + 2, sHalo[0]);
    } else {
        COMPUTE(kt_lo + 1, sHalo[1]);
    }

    // epilogue: C/D layout col=lane&15 (n), row=quad*4+reg (co within 16-tile)
    const int coB = quad * 4;
    float bs[2][4];
#pragma unroll
    for (int mt = 0; mt < 2; ++mt)
#pragma unroll
        for (int reg = 0; reg < 4; ++reg) bs[mt][reg] = sBsum[mt * 16 + coB + reg];

#pragma unroll
    for (int mt = 0; mt < 2; ++mt)
#pragma unroll
        for (int tl = 0; tl < 5; ++tl) {
            int n = wid * 80 + tl * 16 + nl;
            int hh = n / 40;
            int ww = n - hh * 40;
            const size_t base = (size_t)(((b * 32 + mt * 16 + coB) * 16 + o)) * 64000
                              + d * 1600 + (h0 + hh) * 40 + ww;
#pragma unroll
            for (int reg = 0; reg < 4; ++reg)
                out[base + (size_t)reg * 1024000] = acc[mt][tl][reg] + bs[mt][reg];
        }
}

extern "C" void kernel_launch(void* const* d_in, const int* in_sizes, int n_in,
                              void* d_out, int out_size, void* d_ws, size_t ws_size,
                              hipStream_t stream)
{
    const float* x    = (const float*)d_in[0];
    const float* wgt  = (const float*)d_in[1];
    const float* bias = (const float*)d_in[2];
    float* out = (float*)d_out;
    u16* wfbuf = (u16*)d_ws;                                  // 43008 B
    u16* xtp   = (u16*)((char*)d_ws + XT_OFF_BYTES);          // 37,933,056 B
    (void)in_sizes; (void)n_in; (void)out_size; (void)ws_size;

    prep_xw<<<dim3(9345), dim3(256), 0, stream>>>(x, wgt, xtp, wfbuf);
    conv4d_mfma<<<dim3(6400), dim3(256), 0, stream>>>(xtp, wfbuf, bias, out);
}

// Round 4
// 365.251 us; speedup vs baseline: 1.0165x; 1.0165x over previous
//
#include <hip/hip_runtime.h>

// Conv4d: x(2,8,16,40,40,40) f32 * w(3,32,8,3,3,3) + bias(3,32) -> out(2,32,16,40,40,40) f32
// Round 5: 2-o blocks, stage-all-upfront, single barrier per block.
//   prep_xw: fused x-transpose (blocks <9261) + weight-fragment prep (blocks >=9261).
//   main:    block=(b, o-pair, d, h-tile8), 512 thr (8 waves).
//            Waves 0-3 -> o=ob, waves 4-7 -> o=ob+1 (each: 32co x 320n, 5 n-tiles/wave).
//            4 t-planes {ob-1..ob+2} staged up-front into LDS (80.6 KB), ONE __syncthreads
//            drain per block; 2 blocks/CU (LDS 161.8/163.8 KB), 16 waves/CU at VGPR<=128.
//            A-frags read per-s directly from wf (L1/L2-hot, coalesced 1024B/wave).

typedef unsigned int u32;
typedef unsigned short u16;
typedef __attribute__((ext_vector_type(8))) short short8;
typedef __attribute__((ext_vector_type(4))) float f32x4;

#define XT_OFF_BYTES 65536
// x_t strides in elements (bf16): ci 1, wp 8, hp 336, dp 14112, t 592704, b 9483264

__device__ __forceinline__ u32 bf16r(float f) {
    u32 u = __float_as_uint(f);
    return (u + 0x7FFFu + ((u >> 16) & 1u)) >> 16;
}

__device__ __forceinline__ void glds16(const void* g, void* l) {
    __builtin_amdgcn_global_load_lds((const __attribute__((address_space(1))) u32*)g,
                                     (__attribute__((address_space(3))) u32*)l, 16, 0, 0);
}

// ---------- fused pre-kernel: x transpose/pad/convert + weight A-fragment prep ----------
__global__ __launch_bounds__(256) void prep_xw(const float* __restrict__ x,
                                               const float* __restrict__ wgt,
                                               u16* __restrict__ xtp,
                                               u16* __restrict__ wf) {
    if (blockIdx.x >= 9261) {
        // ---- weights -> A-fragment order: Wf[kt][s 7][mt 2][lane 64][j 8], K=216 pad 224 ----
        const int idx = (blockIdx.x - 9261) * 256 + threadIdx.x;   // 21504 total = 3*14*512
        const int kt = idx / 7168;
        const int r  = idx - kt * 7168;
        const int s2 = r >> 9;              // s*2 + mt
        const int l  = (r >> 3) & 63;
        const int j  = r & 7;
        const int co = (s2 & 1) * 16 + (l & 15);
        const int k  = (s2 >> 1) * 32 + (l >> 4) * 8 + j;
        u32 v = 0;
        if (k < 216) {
            const int ci = k & 7;
            const int combo = k >> 3;                         // (kd,kh,kw)
            const int kd = combo / 9;
            const int r9 = combo - kd * 9;
            const int kh = r9 / 3;
            const int kw = r9 - kh * 3;
            v = bf16r(wgt[((kt * 32 + co) * 8 + ci) * 27 + kd * 9 + kh * 3 + kw]);
        }
        wf[idx] = (u16)v;
        return;
    }
    // ---- x -> x_t[b][t][dp 42][hp 42][wp 42][ci 8] bf16, zero-padded halo ----
    const int c = blockIdx.x * 256 + threadIdx.x;        // cell over [b][t][dp][hp][wp], 2370816 total
    int wp = c % 42;
    int tmp = c / 42;
    const int hp = tmp % 42; tmp /= 42;
    const int dp = tmp % 42; tmp /= 42;
    const int t  = tmp % 16;
    const int b  = tmp / 16;
    const int wa = wp - 1, ha = hp - 1, da = dp - 1;
    u32 q0 = 0, q1 = 0, q2 = 0, q3 = 0;
    if ((unsigned)wa < 40u && (unsigned)ha < 40u && (unsigned)da < 40u) {
        const float* xp = x + ((b * 8) * 16 + t) * 64000 + da * 1600 + ha * 40 + wa;
        float v0 = xp[0];
        float v1 = xp[1024000];
        float v2 = xp[2048000];
        float v3 = xp[3072000];
        float v4 = xp[4096000];
        float v5 = xp[5120000];
        float v6 = xp[6144000];
        float v7 = xp[7168000];
        q0 = bf16r(v0) | (bf16r(v1) << 16);
        q1 = bf16r(v2) | (bf16r(v3) << 16);
        q2 = bf16r(v4) | (bf16r(v5) << 16);
        q3 = bf16r(v6) | (bf16r(v7) << 16);
    }
    uint4 q; q.x = q0; q.y = q1; q.z = q2; q.w = q3;
    *(uint4*)(xtp + (size_t)c * 8) = q;
}

// ---------- main kernel ----------
__global__ __launch_bounds__(512, 4) void conv4d_mfma(
    const u16* __restrict__ xtp, const u16* __restrict__ wf,
    const float* __restrict__ bias, float* __restrict__ out)
{
    __shared__ __align__(16) u16 sHalo[4][10080];  // 4 x 20160 B: planes t = ob-1 .. ob+2
    __shared__ float sBsum[2][32];

    const int tid  = threadIdx.x;
    const int lane = tid & 63;
    const int wid  = tid >> 6;          // 0..7
    const int g    = wid >> 2;          // o-group: 0 or 1
    const int w4   = wid & 3;           // wave within group
    const int bi   = blockIdx.x;
    const int h0   = (bi % 5) * 8;
    const int d    = (bi / 5) % 40;
    const int ob   = ((bi / 200) & 7) * 2;   // 0,2,..,14
    const int b    = bi / 1600;

    if (tid < 64) {
        const int gg = tid >> 5;
        const int co = tid & 31;
        const int oo = ob + gg;
        float s = 0.f;
        for (int kt = 0; kt < 3; ++kt) {
            int t = oo + kt - 1;
            if ((unsigned)t < 16u) s += bias[kt * 32 + co];
        }
        sBsum[gg][co] = s;
    }

    const int quad = lane >> 4;
    const int nl   = lane & 15;
    const int o    = ob + g;

    // per-lane n positions (5 n-tiles of 16, 80 n per wave, within the o-group)
    int lb[5];
#pragma unroll
    for (int tl = 0; tl < 5; ++tl) {
        int n = w4 * 80 + tl * 16 + nl;    // 0..319
        int hh = n / 40;
        int ww = n - hh * 40;
        lb[tl] = (hh * 42 + ww) * 16;      // byte offset of cell (h'=hh, w'=ww) at d'=0
    }

    // per-lane combo offset per K-step (combo = 4s + quad), bytes
    int offs7[7];
#pragma unroll
    for (int s = 0; s < 7; ++s) {
        const int c0 = 4 * s;
        int O0 = (c0+0 < 27) ? (((c0+0)/9)*420 + (((c0+0)%9)/3)*42 + ((c0+0)%3)) * 16 : 0;
        int O1 = (c0+1 < 27) ? (((c0+1)/9)*420 + (((c0+1)%9)/3)*42 + ((c0+1)%3)) * 16 : 0;
        int O2 = (c0+2 < 27) ? (((c0+2)/9)*420 + (((c0+2)%9)/3)*42 + ((c0+2)%3)) * 16 : 0;
        int O3 = (c0+3 < 27) ? (((c0+3)/9)*420 + (((c0+3)%9)/3)*42 + ((c0+3)%3)) * 16 : 0;
        offs7[s] = (quad & 2) ? ((quad & 1) ? O3 : O2) : ((quad & 1) ? O1 : O0);
    }

    // ---- stage up to 4 t-planes: 5040 x 16B chunks over 512 threads ----
    {
        const u16* gb = xtp + (size_t)(b * 16) * 592704 + h0 * 336 + d * 14112;
#pragma unroll
        for (int i = 0; i < 10; ++i) {
            const int j = i * 512 + tid;
            if (i < 9 || j < 5040) {
                const int pl  = j / 1260;          // plane slot 0..3
                const int r1  = j - pl * 1260;
                const int t   = ob - 1 + pl;
                if ((unsigned)t < 16u) {
                    const int dpp = r1 / 420;      // 0..2
                    const int row = r1 - dpp * 420;
                    glds16(gb + (size_t)t * 592704 + dpp * 14112 + row * 8,
                           (char*)sHalo + (size_t)(i * 512 + wid * 64) * 16);
                }
            }
        }
    }

    const f32x4 zero = {0.f, 0.f, 0.f, 0.f};
    f32x4 acc[2][5];
#pragma unroll
    for (int mt = 0; mt < 2; ++mt)
#pragma unroll
        for (int tl = 0; tl < 5; ++tl) acc[mt][tl] = zero;

    __syncthreads();     // single drain per block: all 4 planes + sBsum ready

// K-loop body: 7 steps of K=32 (4 combos/step); A-frags direct from global (L1/L2-hot)
#define COMPUTE(KT, BUF)                                                                 \
    {                                                                                    \
        const u16* wfk_ = wf + (KT) * 7168;                                              \
        _Pragma("unroll")                                                                \
        for (int s_ = 0; s_ < 7; ++s_) {                                                 \
            const short8 a0_ = *(const short8*)(wfk_ + s_ * 1024 + lane * 8);            \
            const short8 a1_ = *(const short8*)(wfk_ + s_ * 1024 + 512 + lane * 8);      \
            const int off_ = offs7[s_];                                                  \
            _Pragma("unroll")                                                            \
            for (int tl_ = 0; tl_ < 5; ++tl_) {                                          \
                const short8 bf_ = *(const short8*)((const char*)(BUF) + lb[tl_] + off_);\
                acc[0][tl_] = __builtin_amdgcn_mfma_f32_16x16x32_bf16(a0_, bf_, acc[0][tl_], 0, 0, 0); \
                acc[1][tl_] = __builtin_amdgcn_mfma_f32_16x16x32_bf16(a1_, bf_, acc[1][tl_], 0, 0, 0); \
            }                                                                            \
        }                                                                                \
    }

    // group g computes o = ob+g using plane slots g+kt (wave-uniform branches)
#pragma unroll
    for (int kt = 0; kt < 3; ++kt) {
        if ((unsigned)(o + kt - 1) < 16u) {
            COMPUTE(kt, sHalo[g + kt]);
        }
    }

    // epilogue: C/D layout col=lane&15 (n), row=quad*4+reg (co within 16-tile)
    const int coB = quad * 4;
    float bs[2][4];
#pragma unroll
    for (int mt = 0; mt < 2; ++mt)
#pragma unroll
        for (int reg = 0; reg < 4; ++reg) bs[mt][reg] = sBsum[g][mt * 16 + coB + reg];

#pragma unroll
    for (int mt = 0; mt < 2; ++mt)
#pragma unroll
        for (int tl = 0; tl < 5; ++tl) {
            int n = w4 * 80 + tl * 16 + nl;
            int hh = n / 40;
            int ww = n - hh * 40;
            const size_t base = (size_t)(((b * 32 + mt * 16 + coB) * 16 + o)) * 64000
                              + d * 1600 + (h0 + hh) * 40 + ww;
#pragma unroll
            for (int reg = 0; reg < 4; ++reg)
                out[base + (size_t)reg * 1024000] = acc[mt][tl][reg] + bs[mt][reg];
        }
}

extern "C" void kernel_launch(void* const* d_in, const int* in_sizes, int n_in,
                              void* d_out, int out_size, void* d_ws, size_t ws_size,
                              hipStream_t stream)
{
    const float* x    = (const float*)d_in[0];
    const float* wgt  = (const float*)d_in[1];
    const float* bias = (const float*)d_in[2];
    float* out = (float*)d_out;
    u16* wfbuf = (u16*)d_ws;                                  // 43008 B
    u16* xtp   = (u16*)((char*)d_ws + XT_OFF_BYTES);          // 37,933,056 B
    (void)in_sizes; (void)n_in; (void)out_size; (void)ws_size;

    prep_xw<<<dim3(9345), dim3(256), 0, stream>>>(x, wgt, xtp, wfbuf);
    conv4d_mfma<<<dim3(3200), dim3(512), 0, stream>>>(xtp, wfbuf, bias, out);
}